// Round 1
// baseline (1489.319 us; speedup 1.0000x reference)
//
#include <hip/hip_runtime.h>

#define HID 128
#define TWO_HID 256

// ---------- CSR build ----------
__global__ void k_zero(int* __restrict__ p, int n){
  int i = blockIdx.x*blockDim.x + threadIdx.x;
  if (i < n) p[i] = 0;
}

__global__ void k_deg(const int* __restrict__ dst, int* __restrict__ deg, int E){
  int e = blockIdx.x*blockDim.x + threadIdx.x;
  if (e < E) atomicAdd(&deg[dst[e]], 1);
}

__global__ __launch_bounds__(1024) void k_scan(const int* __restrict__ deg, int* __restrict__ offs,
                                               float* __restrict__ inv_deg, int N, int E){
  __shared__ int part[1024];
  const int tid = threadIdx.x;
  const int CH = (N + 1023) >> 10;
  const int base = tid * CH;
  int s = 0;
  for (int j=0;j<CH;j++){ int i=base+j; if (i<N) s += deg[i]; }
  part[tid] = s;
  __syncthreads();
  for (int off=1; off<1024; off<<=1){
    int t = (tid>=off) ? part[tid-off] : 0;
    __syncthreads();
    part[tid] += t;
    __syncthreads();
  }
  int ex = (tid==0) ? 0 : part[tid-1];
  for (int j=0;j<CH;j++){
    int i=base+j;
    if (i<N){
      offs[i] = ex;
      int d = deg[i];
      ex += d;
      inv_deg[i] = 1.0f / (float)(d>1?d:1);
    }
  }
  if (tid==1023) offs[N] = E;
}

__global__ void k_fill(const int* __restrict__ src, const int* __restrict__ dst,
                       const int* __restrict__ offs, int* __restrict__ cursor,
                       int* __restrict__ ssrc, int E){
  int e = blockIdx.x*blockDim.x + threadIdx.x;
  if (e < E){
    int d = dst[e];
    int pos = offs[d] + atomicAdd(&cursor[d], 1);
    ssrc[pos] = src[e];
  }
}

// ---------- input embedding GEMM: h = h0 @ Wemb^T + bemb ----------
__global__ __launch_bounds__(256) void k_embed(const float* __restrict__ h0, const float* __restrict__ W,
                                               const float* __restrict__ b, float* __restrict__ h, int N){
  const int tid = threadIdx.x;
  const int ty = tid >> 7;      // K-half
  const int o  = tid & 127;     // output col
  float w[64];
  const float* wp = W + o*HID + ty*64;
  #pragma unroll
  for (int i=0;i<64;i+=4){
    float4 t = *(const float4*)(wp + i);
    w[i]=t.x; w[i+1]=t.y; w[i+2]=t.z; w[i+3]=t.w;
  }
  const float bias = b[o];
  __shared__ float part[128];
  for (int r = blockIdx.x; r < N; r += gridDim.x){
    const float* a = h0 + (size_t)r*HID + ty*64;
    float a0=0.f,a1=0.f,a2=0.f,a3=0.f;
    #pragma unroll
    for (int i=0;i<64;i+=4){
      a0 = fmaf(a[i],   w[i],   a0);
      a1 = fmaf(a[i+1], w[i+1], a1);
      a2 = fmaf(a[i+2], w[i+2], a2);
      a3 = fmaf(a[i+3], w[i+3], a3);
    }
    float acc = (a0+a1)+(a2+a3);
    if (ty==1) part[o] = acc;
    __syncthreads();
    if (ty==0) h[(size_t)r*HID + o] = acc + part[o] + bias;
    __syncthreads();
  }
}

// ---------- mean aggregation: c[v] = inv_deg[v] * sum_{e in in(v)} h[src_e] ----------
__global__ __launch_bounds__(256) void k_agg(const float* __restrict__ h, const int* __restrict__ offs,
                                             const int* __restrict__ ssrc, const float* __restrict__ inv_deg,
                                             float* __restrict__ c, float* __restrict__ colsums, int N){
  if (blockIdx.x==0 && threadIdx.x<256) colsums[threadIdx.x] = 0.f;  // zero BN accumulators for this layer
  int gid = blockIdx.x*blockDim.x + threadIdx.x;
  int node = gid >> 6;       // one wave per node
  int lane = gid & 63;       // lane handles float2 (2 features)
  if (node >= N) return;
  int e0 = offs[node], e1 = offs[node+1];
  float accx = 0.f, accy = 0.f;
  const float2* hp = (const float2*)h;
  int e = e0;
  for (; e + 1 < e1; e += 2){
    int s0 = ssrc[e], s1 = ssrc[e+1];
    float2 v0 = hp[(size_t)s0*64 + lane];
    float2 v1 = hp[(size_t)s1*64 + lane];
    accx += v0.x + v1.x; accy += v0.y + v1.y;
  }
  if (e < e1){
    int s0 = ssrc[e];
    float2 v0 = hp[(size_t)s0*64 + lane];
    accx += v0.x; accy += v0.y;
  }
  float id = inv_deg[node];
  ((float2*)c)[(size_t)node*64 + lane] = make_float2(accx*id, accy*id);
}

// ---------- layer GEMM + L2norm + relu + BN partial sums ----------
// z = concat(h,c) @ W^T + b ; z = relu(z/max(||z||,1e-12)) ; colsums += per-col {sum, sumsq}
__global__ __launch_bounds__(256, 2) void k_gemm(const float* __restrict__ h, const float* __restrict__ c,
                                                 const float* __restrict__ W, const float* __restrict__ b,
                                                 float* __restrict__ z, float* __restrict__ colsums, int N){
  const int tid = threadIdx.x;
  const int ty = tid >> 7;      // 0: h-half of K, 1: c-half of K (wave-uniform)
  const int o  = tid & 127;
  float w[128];
  const float* wp = W + o*TWO_HID + ty*HID;
  #pragma unroll
  for (int i=0;i<128;i+=4){
    float4 t = *(const float4*)(wp + i);
    w[i]=t.x; w[i+1]=t.y; w[i+2]=t.z; w[i+3]=t.w;
  }
  const float bias = b[o];
  const float* Abase = ty ? c : h;
  float s1 = 0.f, s2 = 0.f;
  __shared__ float part[128];
  __shared__ float red[2];
  for (int r = blockIdx.x; r < N; r += gridDim.x){
    const float* a = Abase + (size_t)r*HID;
    float a0=0.f,a1=0.f,a2=0.f,a3=0.f;
    #pragma unroll
    for (int i=0;i<128;i+=4){
      a0 = fmaf(a[i],   w[i],   a0);
      a1 = fmaf(a[i+1], w[i+1], a1);
      a2 = fmaf(a[i+2], w[i+2], a2);
      a3 = fmaf(a[i+3], w[i+3], a3);
    }
    float acc = (a0+a1)+(a2+a3);
    if (ty==1) part[o] = acc;
    __syncthreads();
    float zp = 0.f;
    if (ty==0){
      zp = acc + part[o] + bias;
      float ss = zp*zp;
      #pragma unroll
      for (int m=1;m<=32;m<<=1) ss += __shfl_xor(ss, m, 64);
      if ((o & 63)==0) red[o>>6] = ss;
    }
    __syncthreads();
    if (ty==0){
      float tot = red[0] + red[1];
      float nrm = fmaxf(sqrtf(tot), 1e-12f);
      float zr = fmaxf(zp / nrm, 0.f);
      z[(size_t)r*HID + o] = zr;
      s1 += zr;
      s2 += zr*zr;
    }
    __syncthreads();  // protect part[] and red[] before next row
  }
  if (ty==0){
    atomicAdd(&colsums[o],      s1);
    atomicAdd(&colsums[128+o],  s2);
  }
}

// ---------- BN stats finalize ----------
__global__ void k_bnstats(const float* __restrict__ colsums, const float* __restrict__ gamma,
                          const float* __restrict__ beta, float* __restrict__ scsh, int N){
  int o = threadIdx.x;
  float invN = 1.0f / (float)N;
  float mu  = colsums[o]     * invN;
  float var = colsums[128+o] * invN - mu*mu;
  float sc = gamma[o] * rsqrtf(var + 1e-5f);
  scsh[o]      = sc;
  scsh[128+o]  = beta[o] - mu*sc;
}

// ---------- BN apply + residual: h = h + z*sc + sh ----------
__global__ __launch_bounds__(256) void k_bn(const float* __restrict__ z, const float* __restrict__ scsh,
                                            float* __restrict__ h, int Nq){  // Nq = N*32 float4s
  int i = blockIdx.x*blockDim.x + threadIdx.x;
  if (i >= Nq) return;
  int oq = i & 31;  // float4 index within row
  float4 sc = ((const float4*)scsh)[oq];
  float4 sh = ((const float4*)scsh)[32 + oq];
  float4 zv = ((const float4*)z)[i];
  float4 hv = ((float4*)h)[i];
  hv.x = fmaf(zv.x, sc.x, hv.x + sh.x);
  hv.y = fmaf(zv.y, sc.y, hv.y + sh.y);
  hv.z = fmaf(zv.z, sc.z, hv.z + sh.z);
  hv.w = fmaf(zv.w, sc.w, hv.w + sh.w);
  ((float4*)h)[i] = hv;
}

extern "C" void kernel_launch(void* const* d_in, const int* in_sizes, int n_in,
                              void* d_out, int out_size, void* d_ws, size_t ws_size,
                              hipStream_t stream){
  const float* h0   = (const float*)d_in[0];
  const int*   src  = (const int*)d_in[1];
  const int*   dst  = (const int*)d_in[2];
  const float* Wemb = (const float*)d_in[3];
  const float* bemb = (const float*)d_in[4];
  const float* Ws   = (const float*)d_in[5];
  const float* bs   = (const float*)d_in[6];
  const float* gam  = (const float*)d_in[7];
  const float* bet  = (const float*)d_in[8];
  const int N = in_sizes[0] / HID;
  const int E = in_sizes[1];
  float* h = (float*)d_out;

  // workspace carve-out (256B aligned slices); total ~44.5 MB
  char* ws = (char*)d_ws;
  size_t off = 0;
  auto alloc = [&](size_t bytes)->char*{
    char* p = ws + off;
    off = (off + bytes + 255) & ~(size_t)255;
    return p;
  };
  int*   deg     = (int*)  alloc((size_t)N*4);        // contiguous with cursor (N*4 is 256B-multiple)
  int*   cursor  = (int*)  alloc((size_t)N*4);
  int*   offs    = (int*)  alloc((size_t)(N+1)*4);
  float* invd    = (float*)alloc((size_t)N*4);
  int*   ssrc    = (int*)  alloc((size_t)E*4);
  float* c       = (float*)alloc((size_t)N*HID*4);
  float* zb      = (float*)alloc((size_t)N*HID*4);
  float* colsums = (float*)alloc(256*4);
  float* scsh    = (float*)alloc(256*4);

  // CSR build (ws is poisoned each call -> re-zero)
  hipLaunchKernelGGL(k_zero, dim3((2*N+255)/256), dim3(256), 0, stream, deg, 2*N);
  hipLaunchKernelGGL(k_deg,  dim3((E+255)/256),   dim3(256), 0, stream, dst, deg, E);
  hipLaunchKernelGGL(k_scan, dim3(1), dim3(1024), 0, stream, deg, offs, invd, N, E);
  hipLaunchKernelGGL(k_fill, dim3((E+255)/256),   dim3(256), 0, stream, src, dst, offs, cursor, ssrc, E);

  // input embedding
  hipLaunchKernelGGL(k_embed, dim3(512), dim3(256), 0, stream, h0, Wemb, bemb, h, N);

  for (int l=0;l<4;l++){
    hipLaunchKernelGGL(k_agg, dim3((N*64+255)/256), dim3(256), 0, stream,
                       h, offs, ssrc, invd, c, colsums, N);
    hipLaunchKernelGGL(k_gemm, dim3(512), dim3(256), 0, stream,
                       h, c, Ws + (size_t)l*HID*TWO_HID, bs + (size_t)l*HID, zb, colsums, N);
    hipLaunchKernelGGL(k_bnstats, dim3(1), dim3(128), 0, stream,
                       colsums, gam + (size_t)l*HID, bet + (size_t)l*HID, scsh, N);
    hipLaunchKernelGGL(k_bn, dim3((N*32+255)/256), dim3(256), 0, stream, zb, scsh, h, N*32);
  }
}

// Round 3
// 599.271 us; speedup vs baseline: 2.4852x; 2.4852x over previous
//
#include <hip/hip_runtime.h>

#define HID 128
#define TWO_HID 256

typedef __attribute__((ext_vector_type(8))) short short8;
typedef __attribute__((ext_vector_type(4))) float f32x4;

__device__ inline unsigned short f2b(float f){
  unsigned u = __float_as_uint(f);
  unsigned r = u + 0x7FFFu + ((u >> 16) & 1u);   // RNE
  return (unsigned short)(r >> 16);
}
__device__ inline unsigned pack2(float lo, float hi){
  return (unsigned)f2b(lo) | ((unsigned)f2b(hi) << 16);
}
__device__ inline float blo(unsigned u){ return __uint_as_float(u << 16); }
__device__ inline float bhi(unsigned u){ return __uint_as_float(u & 0xFFFF0000u); }

// ---------- CSR build ----------
__global__ void k_zero(int* __restrict__ p, int n){
  int i = blockIdx.x*blockDim.x + threadIdx.x;
  if (i < n) p[i] = 0;
}

__global__ void k_deg(const int* __restrict__ dst, int* __restrict__ deg, int E){
  int e = blockIdx.x*blockDim.x + threadIdx.x;
  if (e < E) atomicAdd(&deg[dst[e]], 1);
}

__global__ __launch_bounds__(1024) void k_scan(const int* __restrict__ deg, int* __restrict__ offs,
                                               float* __restrict__ inv_deg, int N, int E){
  __shared__ int part[1024];
  const int tid = threadIdx.x;
  const int CH = (N + 1023) >> 10;
  const int base = tid * CH;
  int s = 0;
  for (int j=0;j<CH;j++){ int i=base+j; if (i<N) s += deg[i]; }
  part[tid] = s;
  __syncthreads();
  for (int off=1; off<1024; off<<=1){
    int t = (tid>=off) ? part[tid-off] : 0;
    __syncthreads();
    part[tid] += t;
    __syncthreads();
  }
  int ex = (tid==0) ? 0 : part[tid-1];
  for (int j=0;j<CH;j++){
    int i=base+j;
    if (i<N){
      offs[i] = ex;
      int d = deg[i];
      ex += d;
      inv_deg[i] = 1.0f / (float)(d>1?d:1);
    }
  }
  if (tid==1023) offs[N] = E;
}

__global__ void k_fill(const int* __restrict__ src, const int* __restrict__ dst,
                       const int* __restrict__ offs, int* __restrict__ cursor,
                       int* __restrict__ ssrc, int E){
  int e = blockIdx.x*blockDim.x + threadIdx.x;
  if (e < E){
    int d = dst[e];
    int pos = offs[d] + atomicAdd(&cursor[d], 1);
    ssrc[pos] = src[e];
  }
}

// ---------- input embedding: h = h0 @ Wemb^T + b  (MFMA bf16) ----------
// writes h (f32) and the h-half of xb (bf16 [N][256])
__global__ __launch_bounds__(256) void k_embed(const float* __restrict__ h0, const float* __restrict__ W,
                                               const float* __restrict__ b, float* __restrict__ h,
                                               unsigned short* __restrict__ xb, int Ntiles){
  const int tid = threadIdx.x;
  const int w = tid >> 6, l = tid & 63;
  const int l15 = l & 15, lhi = l >> 4;
  const int cb = w * 32;

  short8 bf[2][4];
  #pragma unroll
  for (int t=0;t<2;t++){
    #pragma unroll
    for (int s=0;s<4;s++){
      const float* wp = W + (size_t)(cb + t*16 + l15)*HID + s*32 + lhi*8;
      float4 x0 = *(const float4*)wp;
      float4 x1 = *(const float4*)(wp + 4);
      short8 f;
      f[0]=(short)f2b(x0.x); f[1]=(short)f2b(x0.y); f[2]=(short)f2b(x0.z); f[3]=(short)f2b(x0.w);
      f[4]=(short)f2b(x1.x); f[5]=(short)f2b(x1.y); f[6]=(short)f2b(x1.z); f[7]=(short)f2b(x1.w);
      bf[t][s] = f;
    }
  }
  const float bias0 = b[cb + l15];
  const float bias1 = b[cb + 16 + l15];

  for (int tile = blockIdx.x; tile < Ntiles; tile += gridDim.x){
    const int row0 = tile * 16;
    short8 af[4];
    #pragma unroll
    for (int s=0;s<4;s++){
      const float* ap = h0 + (size_t)(row0 + l15)*HID + s*32 + lhi*8;
      float4 x0 = *(const float4*)ap;
      float4 x1 = *(const float4*)(ap + 4);
      short8 f;
      f[0]=(short)f2b(x0.x); f[1]=(short)f2b(x0.y); f[2]=(short)f2b(x0.z); f[3]=(short)f2b(x0.w);
      f[4]=(short)f2b(x1.x); f[5]=(short)f2b(x1.y); f[6]=(short)f2b(x1.z); f[7]=(short)f2b(x1.w);
      af[s] = f;
    }
    f32x4 acc0 = {0.f,0.f,0.f,0.f}, acc1 = {0.f,0.f,0.f,0.f};
    #pragma unroll
    for (int s=0;s<4;s++){
      acc0 = __builtin_amdgcn_mfma_f32_16x16x32_bf16(af[s], bf[0][s], acc0, 0,0,0);
      acc1 = __builtin_amdgcn_mfma_f32_16x16x32_bf16(af[s], bf[1][s], acc1, 0,0,0);
    }
    #pragma unroll
    for (int r=0;r<4;r++){
      const int row = row0 + lhi*4 + r;
      float v0 = acc0[r] + bias0;
      float v1 = acc1[r] + bias1;
      h[(size_t)row*HID + cb + l15]      = v0;
      h[(size_t)row*HID + cb + 16 + l15] = v1;
      xb[(size_t)row*TWO_HID + cb + l15]      = f2b(v0);
      xb[(size_t)row*TWO_HID + cb + 16 + l15] = f2b(v1);
    }
  }
}

// ---------- mean aggregation over bf16 mirror: xb[:,128:256] = mean of xb[src,0:128] ----------
__global__ __launch_bounds__(256) void k_agg(unsigned* __restrict__ xbu, const int* __restrict__ offs,
                                             const int* __restrict__ ssrc, const float* __restrict__ invd,
                                             float* __restrict__ colsums, int N){
  if (blockIdx.x==0 && threadIdx.x<256) colsums[threadIdx.x] = 0.f;  // zero BN accums for this layer
  int gid = blockIdx.x*blockDim.x + threadIdx.x;
  int node = gid >> 6;
  int lane = gid & 63;     // uint = 2 features
  if (node >= N) return;
  int e0 = offs[node], e1 = offs[node+1];
  float ax = 0.f, ay = 0.f;
  int e = e0;
  for (; e + 1 < e1; e += 2){
    int s0 = ssrc[e], s1 = ssrc[e+1];
    unsigned u0 = xbu[(size_t)s0*128 + lane];
    unsigned u1 = xbu[(size_t)s1*128 + lane];
    ax += blo(u0) + blo(u1);
    ay += bhi(u0) + bhi(u1);
  }
  if (e < e1){
    unsigned u0 = xbu[(size_t)ssrc[e]*128 + lane];
    ax += blo(u0);
    ay += bhi(u0);
  }
  float id = invd[node];
  xbu[(size_t)node*128 + 64 + lane] = pack2(ax*id, ay*id);
}

// ---------- layer GEMM (MFMA bf16) + L2norm + relu + BN partial sums ----------
__global__ __launch_bounds__(256) void k_gemm(const unsigned short* __restrict__ xb,
                                              const float* __restrict__ W, const float* __restrict__ b,
                                              float* __restrict__ z, float* __restrict__ colsums, int Ntiles){
  __shared__ float rowss[2][16][4];
  const int tid = threadIdx.x;
  const int w = tid >> 6, l = tid & 63;
  const int l15 = l & 15, lhi = l >> 4;
  const int cb = w * 32;

  short8 bf[2][8];
  #pragma unroll
  for (int t=0;t<2;t++){
    #pragma unroll
    for (int s=0;s<8;s++){
      const float* wp = W + (size_t)(cb + t*16 + l15)*TWO_HID + s*32 + lhi*8;
      float4 x0 = *(const float4*)wp;
      float4 x1 = *(const float4*)(wp + 4);
      short8 f;
      f[0]=(short)f2b(x0.x); f[1]=(short)f2b(x0.y); f[2]=(short)f2b(x0.z); f[3]=(short)f2b(x0.w);
      f[4]=(short)f2b(x1.x); f[5]=(short)f2b(x1.y); f[6]=(short)f2b(x1.z); f[7]=(short)f2b(x1.w);
      bf[t][s] = f;
    }
  }
  const float bias0 = b[cb + l15];
  const float bias1 = b[cb + 16 + l15];
  float s1a = 0.f, s2a = 0.f, s1b = 0.f, s2b = 0.f;

  int parity = 0;
  for (int tile = blockIdx.x; tile < Ntiles; tile += gridDim.x, parity ^= 1){
    const int row0 = tile * 16;
    short8 af[8];
    #pragma unroll
    for (int s=0;s<8;s++)
      af[s] = *(const short8*)(xb + (size_t)(row0 + l15)*TWO_HID + s*32 + lhi*8);

    f32x4 acc0 = {0.f,0.f,0.f,0.f}, acc1 = {0.f,0.f,0.f,0.f};
    #pragma unroll
    for (int s=0;s<8;s++){
      acc0 = __builtin_amdgcn_mfma_f32_16x16x32_bf16(af[s], bf[0][s], acc0, 0,0,0);
      acc1 = __builtin_amdgcn_mfma_f32_16x16x32_bf16(af[s], bf[1][s], acc1, 0,0,0);
    }

    float v0[4], v1[4], p[4];
    #pragma unroll
    for (int r=0;r<4;r++){
      v0[r] = acc0[r] + bias0;
      v1[r] = acc1[r] + bias1;
      p[r] = v0[r]*v0[r] + v1[r]*v1[r];
    }
    #pragma unroll
    for (int m=1;m<=8;m<<=1){
      #pragma unroll
      for (int r=0;r<4;r++) p[r] += __shfl_xor(p[r], m, 64);
    }
    if (l15 == 0){
      #pragma unroll
      for (int r=0;r<4;r++) rowss[parity][lhi*4+r][w] = p[r];
    }
    __syncthreads();
    #pragma unroll
    for (int r=0;r<4;r++){
      const int i = lhi*4 + r;
      f32x4 q = *(const f32x4*)&rowss[parity][i][0];
      float ss = (q[0]+q[1]) + (q[2]+q[3]);
      float sc = 1.f / fmaxf(sqrtf(ss), 1e-12f);
      float z0 = fmaxf(v0[r]*sc, 0.f);
      float z1 = fmaxf(v1[r]*sc, 0.f);
      z[(size_t)(row0+i)*HID + cb + l15]      = z0;
      z[(size_t)(row0+i)*HID + cb + 16 + l15] = z1;
      s1a += z0; s2a += z0*z0;
      s1b += z1; s2b += z1*z1;
    }
  }
  // reduce BN partials across the 4 lane-groups (same col), then one atomic per col
  s1a += __shfl_xor(s1a,16,64); s1a += __shfl_xor(s1a,32,64);
  s2a += __shfl_xor(s2a,16,64); s2a += __shfl_xor(s2a,32,64);
  s1b += __shfl_xor(s1b,16,64); s1b += __shfl_xor(s1b,32,64);
  s2b += __shfl_xor(s2b,16,64); s2b += __shfl_xor(s2b,32,64);
  if (lhi == 0){
    atomicAdd(&colsums[cb + l15],            s1a);
    atomicAdd(&colsums[128 + cb + l15],      s2a);
    atomicAdd(&colsums[cb + 16 + l15],       s1b);
    atomicAdd(&colsums[128 + cb + 16 + l15], s2b);
  }
}

// ---------- BN stats finalize ----------
__global__ void k_bnstats(const float* __restrict__ colsums, const float* __restrict__ gamma,
                          const float* __restrict__ beta, float* __restrict__ scsh, int N){
  int o = threadIdx.x;
  float invN = 1.0f / (float)N;
  float mu  = colsums[o]     * invN;
  float var = colsums[128+o] * invN - mu*mu;
  float sc = gamma[o] * rsqrtf(var + 1e-5f);
  scsh[o]      = sc;
  scsh[128+o]  = beta[o] - mu*sc;
}

// ---------- BN apply + residual: h += z*sc + sh ; refresh bf16 mirror ----------
__global__ __launch_bounds__(256) void k_bn(const float* __restrict__ z, const float* __restrict__ scsh,
                                            float* __restrict__ h, unsigned* __restrict__ xbu, int Nh){
  int i = blockIdx.x*blockDim.x + threadIdx.x;
  if (i >= Nh) return;
  int j = i & 63;
  int node = i >> 6;
  float2 sc = ((const float2*)scsh)[j];
  float2 sh = ((const float2*)(scsh + 128))[j];
  float2 zv = ((const float2*)z)[i];
  float2 hv = ((const float2*)h)[i];
  float nx = fmaf(zv.x, sc.x, hv.x + sh.x);
  float ny = fmaf(zv.y, sc.y, hv.y + sh.y);
  ((float2*)h)[i] = make_float2(nx, ny);
  xbu[(size_t)node*128 + j] = pack2(nx, ny);
}

extern "C" void kernel_launch(void* const* d_in, const int* in_sizes, int n_in,
                              void* d_out, int out_size, void* d_ws, size_t ws_size,
                              hipStream_t stream){
  const float* h0   = (const float*)d_in[0];
  const int*   src  = (const int*)d_in[1];
  const int*   dst  = (const int*)d_in[2];
  const float* Wemb = (const float*)d_in[3];
  const float* bemb = (const float*)d_in[4];
  const float* Ws   = (const float*)d_in[5];
  const float* bs   = (const float*)d_in[6];
  const float* gam  = (const float*)d_in[7];
  const float* bet  = (const float*)d_in[8];
  const int N = in_sizes[0] / HID;
  const int E = in_sizes[1];
  const int Ntiles = N / 16;
  float* h = (float*)d_out;

  char* ws = (char*)d_ws;
  size_t off = 0;
  auto alloc = [&](size_t bytes)->char*{
    char* p = ws + off;
    off = (off + bytes + 255) & ~(size_t)255;
    return p;
  };
  int*   deg     = (int*)  alloc((size_t)N*4);   // deg+cursor contiguous for k_zero
  int*   cursor  = (int*)  alloc((size_t)N*4);
  int*   offs    = (int*)  alloc((size_t)(N+1)*4);
  float* invd    = (float*)alloc((size_t)N*4);
  int*   ssrc    = (int*)  alloc((size_t)E*4);
  unsigned short* xb = (unsigned short*)alloc((size_t)N*TWO_HID*2);  // bf16 concat(h,c)
  float* zb      = (float*)alloc((size_t)N*HID*4);
  float* colsums = (float*)alloc(256*4);
  float* scsh    = (float*)alloc(256*4);

  hipLaunchKernelGGL(k_zero, dim3((2*N+255)/256), dim3(256), 0, stream, deg, 2*N);
  hipLaunchKernelGGL(k_deg,  dim3((E+255)/256),   dim3(256), 0, stream, dst, deg, E);
  hipLaunchKernelGGL(k_scan, dim3(1), dim3(1024), 0, stream, deg, offs, invd, N, E);
  hipLaunchKernelGGL(k_fill, dim3((E+255)/256),   dim3(256), 0, stream, src, dst, offs, cursor, ssrc, E);

  hipLaunchKernelGGL(k_embed, dim3(512), dim3(256), 0, stream, h0, Wemb, bemb, h, xb, Ntiles);

  for (int l=0;l<4;l++){
    hipLaunchKernelGGL(k_agg, dim3((N*64+255)/256), dim3(256), 0, stream,
                       (unsigned*)xb, offs, ssrc, invd, colsums, N);
    hipLaunchKernelGGL(k_gemm, dim3(512), dim3(256), 0, stream,
                       xb, Ws + (size_t)l*HID*TWO_HID, bs + (size_t)l*HID, zb, colsums, Ntiles);
    hipLaunchKernelGGL(k_bnstats, dim3(1), dim3(128), 0, stream,
                       colsums, gam + (size_t)l*HID, bet + (size_t)l*HID, scsh, N);
    hipLaunchKernelGGL(k_bn, dim3((N*64+255)/256), dim3(256), 0, stream,
                       zb, scsh, h, (unsigned*)xb, N*64);
  }
}

// Round 4
// 464.794 us; speedup vs baseline: 3.2043x; 1.2893x over previous
//
#include <hip/hip_runtime.h>

#define HID 128
#define TWO_HID 256

typedef __attribute__((ext_vector_type(8))) short short8;
typedef __attribute__((ext_vector_type(4))) float f32x4;

__device__ inline unsigned short f2b(float f){
  unsigned u = __float_as_uint(f);
  unsigned r = u + 0x7FFFu + ((u >> 16) & 1u);   // RNE
  return (unsigned short)(r >> 16);
}
__device__ inline unsigned pack2(float lo, float hi){
  return (unsigned)f2b(lo) | ((unsigned)f2b(hi) << 16);
}
__device__ inline float blo(unsigned u){ return __uint_as_float(u << 16); }
__device__ inline float bhi(unsigned u){ return __uint_as_float(u & 0xFFFF0000u); }

// ---------- CSR build ----------
__global__ void k_zero(int* __restrict__ p, int n){
  int i = blockIdx.x*blockDim.x + threadIdx.x;
  if (i < n) p[i] = 0;
}

__global__ void k_deg(const int* __restrict__ dst, int* __restrict__ deg, int E){
  int e = blockIdx.x*blockDim.x + threadIdx.x;
  if (e < E) atomicAdd(&deg[dst[e]], 1);
}

// multi-block exclusive scan: pass 1 (per-block scan + block sums)
__global__ __launch_bounds__(256) void k_scan1(const int* __restrict__ deg, int* __restrict__ loc,
                                               int* __restrict__ bsum, int N){
  const int tid = threadIdx.x;
  const int i = blockIdx.x*256 + tid;
  const int lane = tid & 63, wv = tid >> 6;
  int v = (i < N) ? deg[i] : 0;
  int s = v;
  #pragma unroll
  for (int m=1; m<64; m<<=1){
    int t = __shfl_up(s, m, 64);
    if (lane >= m) s += t;
  }
  __shared__ int wsum[4];
  if (lane == 63) wsum[wv] = s;
  __syncthreads();
  if (tid == 0){
    int a = 0;
    #pragma unroll
    for (int w2=0; w2<4; w2++){ int t = wsum[w2]; wsum[w2] = a; a += t; }
    bsum[blockIdx.x] = a;
  }
  __syncthreads();
  if (i < N) loc[i] = s - v + wsum[wv];
}

// pass 2: exclusive scan of block sums (nb <= 256), single block
__global__ __launch_bounds__(256) void k_scan2(int* __restrict__ bsum, int nb){
  const int tid = threadIdx.x;
  const int lane = tid & 63, wv = tid >> 6;
  int v = (tid < nb) ? bsum[tid] : 0;
  int s = v;
  #pragma unroll
  for (int m=1; m<64; m<<=1){
    int t = __shfl_up(s, m, 64);
    if (lane >= m) s += t;
  }
  __shared__ int wsum[4];
  if (lane == 63) wsum[wv] = s;
  __syncthreads();
  if (tid == 0){
    int a = 0;
    #pragma unroll
    for (int w2=0; w2<4; w2++){ int t = wsum[w2]; wsum[w2] = a; a += t; }
  }
  __syncthreads();
  if (tid < nb) bsum[tid] = s - v + wsum[wv];
}

// pass 3: offs = loc + bsum[block]; invd; offs[N]=E   (grid/block MUST match pass 1)
__global__ __launch_bounds__(256) void k_scan3(const int* __restrict__ deg, const int* __restrict__ loc,
                                               const int* __restrict__ bsum, int* __restrict__ offs,
                                               float* __restrict__ invd, int N, int E){
  const int i = blockIdx.x*256 + threadIdx.x;
  if (i < N){
    offs[i] = loc[i] + bsum[blockIdx.x];
    int d = deg[i];
    invd[i] = 1.0f / (float)(d>1?d:1);
  }
  if (i == 0) offs[N] = E;
}

__global__ void k_fill(const int* __restrict__ src, const int* __restrict__ dst,
                       const int* __restrict__ offs, int* __restrict__ cursor,
                       int* __restrict__ ssrc, int E){
  int e = blockIdx.x*blockDim.x + threadIdx.x;
  if (e < E){
    int d = dst[e];
    int pos = offs[d] + atomicAdd(&cursor[d], 1);
    ssrc[pos] = src[e];
  }
}

// ---------- input embedding: h = h0 @ Wemb^T + b  (MFMA bf16) ----------
__global__ __launch_bounds__(256) void k_embed(const float* __restrict__ h0, const float* __restrict__ W,
                                               const float* __restrict__ b, float* __restrict__ h,
                                               unsigned short* __restrict__ xb, int Ntiles){
  const int tid = threadIdx.x;
  const int w = tid >> 6, l = tid & 63;
  const int l15 = l & 15, lhi = l >> 4;
  const int cb = w * 32;

  short8 bf[2][4];
  #pragma unroll
  for (int t=0;t<2;t++){
    #pragma unroll
    for (int s=0;s<4;s++){
      const float* wp = W + (size_t)(cb + t*16 + l15)*HID + s*32 + lhi*8;
      float4 x0 = *(const float4*)wp;
      float4 x1 = *(const float4*)(wp + 4);
      short8 f;
      f[0]=(short)f2b(x0.x); f[1]=(short)f2b(x0.y); f[2]=(short)f2b(x0.z); f[3]=(short)f2b(x0.w);
      f[4]=(short)f2b(x1.x); f[5]=(short)f2b(x1.y); f[6]=(short)f2b(x1.z); f[7]=(short)f2b(x1.w);
      bf[t][s] = f;
    }
  }
  const float bias0 = b[cb + l15];
  const float bias1 = b[cb + 16 + l15];

  for (int tile = blockIdx.x; tile < Ntiles; tile += gridDim.x){
    const int row0 = tile * 16;
    short8 af[4];
    #pragma unroll
    for (int s=0;s<4;s++){
      const float* ap = h0 + (size_t)(row0 + l15)*HID + s*32 + lhi*8;
      float4 x0 = *(const float4*)ap;
      float4 x1 = *(const float4*)(ap + 4);
      short8 f;
      f[0]=(short)f2b(x0.x); f[1]=(short)f2b(x0.y); f[2]=(short)f2b(x0.z); f[3]=(short)f2b(x0.w);
      f[4]=(short)f2b(x1.x); f[5]=(short)f2b(x1.y); f[6]=(short)f2b(x1.z); f[7]=(short)f2b(x1.w);
      af[s] = f;
    }
    f32x4 acc0 = {0.f,0.f,0.f,0.f}, acc1 = {0.f,0.f,0.f,0.f};
    #pragma unroll
    for (int s=0;s<4;s++){
      acc0 = __builtin_amdgcn_mfma_f32_16x16x32_bf16(af[s], bf[0][s], acc0, 0,0,0);
      acc1 = __builtin_amdgcn_mfma_f32_16x16x32_bf16(af[s], bf[1][s], acc1, 0,0,0);
    }
    #pragma unroll
    for (int r=0;r<4;r++){
      const int row = row0 + lhi*4 + r;
      float v0 = acc0[r] + bias0;
      float v1 = acc1[r] + bias1;
      h[(size_t)row*HID + cb + l15]      = v0;
      h[(size_t)row*HID + cb + 16 + l15] = v1;
      xb[(size_t)row*TWO_HID + cb + l15]      = f2b(v0);
      xb[(size_t)row*TWO_HID + cb + 16 + l15] = f2b(v1);
    }
  }
}

// ---------- mean aggregation over bf16 mirror ----------
__global__ __launch_bounds__(256) void k_agg(unsigned* __restrict__ xbu, const int* __restrict__ offs,
                                             const int* __restrict__ ssrc, const float* __restrict__ invd,
                                             float* __restrict__ colsums, int N){
  if (blockIdx.x==0 && threadIdx.x<256) colsums[threadIdx.x] = 0.f;  // zero BN accums for this layer
  int gid = blockIdx.x*blockDim.x + threadIdx.x;
  int node = gid >> 6;
  int lane = gid & 63;     // uint = 2 features
  if (node >= N) return;
  int e0 = offs[node], e1 = offs[node+1];
  float ax = 0.f, ay = 0.f;
  int e = e0;
  for (; e + 3 < e1; e += 4){
    int s0 = ssrc[e], s1 = ssrc[e+1], s2 = ssrc[e+2], s3 = ssrc[e+3];
    unsigned u0 = xbu[(size_t)s0*128 + lane];
    unsigned u1 = xbu[(size_t)s1*128 + lane];
    unsigned u2 = xbu[(size_t)s2*128 + lane];
    unsigned u3 = xbu[(size_t)s3*128 + lane];
    ax += (blo(u0) + blo(u1)) + (blo(u2) + blo(u3));
    ay += (bhi(u0) + bhi(u1)) + (bhi(u2) + bhi(u3));
  }
  for (; e < e1; e++){
    unsigned u0 = xbu[(size_t)ssrc[e]*128 + lane];
    ax += blo(u0);
    ay += bhi(u0);
  }
  float id = invd[node];
  xbu[(size_t)node*128 + 64 + lane] = pack2(ax*id, ay*id);
}

// ---------- layer GEMM (MFMA bf16) + L2norm + relu + BN partial sums ----------
__global__ __launch_bounds__(256) void k_gemm(const unsigned short* __restrict__ xb,
                                              const float* __restrict__ W, const float* __restrict__ b,
                                              float* __restrict__ z, float* __restrict__ colsums, int Ntiles){
  __shared__ float rowss[2][16][4];
  const int tid = threadIdx.x;
  const int w = tid >> 6, l = tid & 63;
  const int l15 = l & 15, lhi = l >> 4;
  const int cb = w * 32;

  short8 bf[2][8];
  #pragma unroll
  for (int t=0;t<2;t++){
    #pragma unroll
    for (int s=0;s<8;s++){
      const float* wp = W + (size_t)(cb + t*16 + l15)*TWO_HID + s*32 + lhi*8;
      float4 x0 = *(const float4*)wp;
      float4 x1 = *(const float4*)(wp + 4);
      short8 f;
      f[0]=(short)f2b(x0.x); f[1]=(short)f2b(x0.y); f[2]=(short)f2b(x0.z); f[3]=(short)f2b(x0.w);
      f[4]=(short)f2b(x1.x); f[5]=(short)f2b(x1.y); f[6]=(short)f2b(x1.z); f[7]=(short)f2b(x1.w);
      bf[t][s] = f;
    }
  }
  const float bias0 = b[cb + l15];
  const float bias1 = b[cb + 16 + l15];
  float s1a = 0.f, s2a = 0.f, s1b = 0.f, s2b = 0.f;

  int parity = 0;
  for (int tile = blockIdx.x; tile < Ntiles; tile += gridDim.x, parity ^= 1){
    const int row0 = tile * 16;
    short8 af[8];
    #pragma unroll
    for (int s=0;s<8;s++)
      af[s] = *(const short8*)(xb + (size_t)(row0 + l15)*TWO_HID + s*32 + lhi*8);

    f32x4 acc0 = {0.f,0.f,0.f,0.f}, acc1 = {0.f,0.f,0.f,0.f};
    #pragma unroll
    for (int s=0;s<8;s++){
      acc0 = __builtin_amdgcn_mfma_f32_16x16x32_bf16(af[s], bf[0][s], acc0, 0,0,0);
      acc1 = __builtin_amdgcn_mfma_f32_16x16x32_bf16(af[s], bf[1][s], acc1, 0,0,0);
    }

    float v0[4], v1[4], p[4];
    #pragma unroll
    for (int r=0;r<4;r++){
      v0[r] = acc0[r] + bias0;
      v1[r] = acc1[r] + bias1;
      p[r] = v0[r]*v0[r] + v1[r]*v1[r];
    }
    #pragma unroll
    for (int m=1;m<=8;m<<=1){
      #pragma unroll
      for (int r=0;r<4;r++) p[r] += __shfl_xor(p[r], m, 64);
    }
    if (l15 == 0){
      #pragma unroll
      for (int r=0;r<4;r++) rowss[parity][lhi*4+r][w] = p[r];
    }
    __syncthreads();
    #pragma unroll
    for (int r=0;r<4;r++){
      const int i = lhi*4 + r;
      f32x4 q = *(const f32x4*)&rowss[parity][i][0];
      float ss = (q[0]+q[1]) + (q[2]+q[3]);
      float sc = 1.f / fmaxf(sqrtf(ss), 1e-12f);
      float z0 = fmaxf(v0[r]*sc, 0.f);
      float z1 = fmaxf(v1[r]*sc, 0.f);
      z[(size_t)(row0+i)*HID + cb + l15]      = z0;
      z[(size_t)(row0+i)*HID + cb + 16 + l15] = z1;
      s1a += z0; s2a += z0*z0;
      s1b += z1; s2b += z1*z1;
    }
  }
  s1a += __shfl_xor(s1a,16,64); s1a += __shfl_xor(s1a,32,64);
  s2a += __shfl_xor(s2a,16,64); s2a += __shfl_xor(s2a,32,64);
  s1b += __shfl_xor(s1b,16,64); s1b += __shfl_xor(s1b,32,64);
  s2b += __shfl_xor(s2b,16,64); s2b += __shfl_xor(s2b,32,64);
  if (lhi == 0){
    atomicAdd(&colsums[cb + l15],            s1a);
    atomicAdd(&colsums[128 + cb + l15],      s2a);
    atomicAdd(&colsums[cb + 16 + l15],       s1b);
    atomicAdd(&colsums[128 + cb + 16 + l15], s2b);
  }
}

// ---------- BN stats (inline) + apply + residual: h += z*sc + sh ; refresh bf16 mirror ----------
__global__ __launch_bounds__(256) void k_bn(const float* __restrict__ z, const float* __restrict__ colsums,
                                            const float* __restrict__ gamma, const float* __restrict__ beta,
                                            float* __restrict__ h, unsigned* __restrict__ xbu,
                                            int Nh, float invN){
  int i = blockIdx.x*blockDim.x + threadIdx.x;
  if (i >= Nh) return;
  int j = i & 63;          // float2 column-pair index
  int node = i >> 6;
  float2 s1 = ((const float2*)colsums)[j];
  float2 s2 = ((const float2*)(colsums + 128))[j];
  float2 g  = ((const float2*)gamma)[j];
  float2 bt = ((const float2*)beta)[j];
  float mux = s1.x*invN,           muy = s1.y*invN;
  float vax = s2.x*invN - mux*mux, vay = s2.y*invN - muy*muy;
  float scx = g.x * rsqrtf(vax + 1e-5f), scy = g.y * rsqrtf(vay + 1e-5f);
  float shx = bt.x - mux*scx,            shy = bt.y - muy*scy;
  float2 zv = ((const float2*)z)[i];
  float2 hv = ((const float2*)h)[i];
  float nx = fmaf(zv.x, scx, hv.x + shx);
  float ny = fmaf(zv.y, scy, hv.y + shy);
  ((float2*)h)[i] = make_float2(nx, ny);
  xbu[(size_t)node*128 + j] = pack2(nx, ny);
}

extern "C" void kernel_launch(void* const* d_in, const int* in_sizes, int n_in,
                              void* d_out, int out_size, void* d_ws, size_t ws_size,
                              hipStream_t stream){
  const float* h0   = (const float*)d_in[0];
  const int*   src  = (const int*)d_in[1];
  const int*   dst  = (const int*)d_in[2];
  const float* Wemb = (const float*)d_in[3];
  const float* bemb = (const float*)d_in[4];
  const float* Ws   = (const float*)d_in[5];
  const float* bs   = (const float*)d_in[6];
  const float* gam  = (const float*)d_in[7];
  const float* bet  = (const float*)d_in[8];
  const int N = in_sizes[0] / HID;
  const int E = in_sizes[1];
  const int Ntiles = N / 16;
  const int NB = (N + 255) / 256;
  float* h = (float*)d_out;

  char* ws = (char*)d_ws;
  size_t off = 0;
  auto alloc = [&](size_t bytes)->char*{
    char* p = ws + off;
    off = (off + bytes + 255) & ~(size_t)255;
    return p;
  };
  int*   deg     = (int*)  alloc((size_t)N*4);   // deg+cursor contiguous for k_zero
  int*   cursor  = (int*)  alloc((size_t)N*4);
  int*   offs    = (int*)  alloc((size_t)(N+1)*4);
  int*   loc     = (int*)  alloc((size_t)N*4);
  int*   bsum    = (int*)  alloc((size_t)NB*4);
  float* invd    = (float*)alloc((size_t)N*4);
  int*   ssrc    = (int*)  alloc((size_t)E*4);
  unsigned short* xb = (unsigned short*)alloc((size_t)N*TWO_HID*2);  // bf16 concat(h,c)
  float* zb      = (float*)alloc((size_t)N*HID*4);
  float* colsums = (float*)alloc(256*4);

  hipLaunchKernelGGL(k_zero,  dim3((2*N+255)/256), dim3(256), 0, stream, deg, 2*N);
  hipLaunchKernelGGL(k_deg,   dim3((E+255)/256),   dim3(256), 0, stream, dst, deg, E);
  hipLaunchKernelGGL(k_scan1, dim3(NB),  dim3(256), 0, stream, deg, loc, bsum, N);
  hipLaunchKernelGGL(k_scan2, dim3(1),   dim3(256), 0, stream, bsum, NB);
  hipLaunchKernelGGL(k_scan3, dim3(NB),  dim3(256), 0, stream, deg, loc, bsum, offs, invd, N, E);
  hipLaunchKernelGGL(k_fill,  dim3((E+255)/256),   dim3(256), 0, stream, src, dst, offs, cursor, ssrc, E);

  hipLaunchKernelGGL(k_embed, dim3(512), dim3(256), 0, stream, h0, Wemb, bemb, h, xb, Ntiles);

  for (int l=0;l<4;l++){
    hipLaunchKernelGGL(k_agg, dim3((N*64+255)/256), dim3(256), 0, stream,
                       (unsigned*)xb, offs, ssrc, invd, colsums, N);
    hipLaunchKernelGGL(k_gemm, dim3(512), dim3(256), 0, stream,
                       xb, Ws + (size_t)l*HID*TWO_HID, bs + (size_t)l*HID, zb, colsums, Ntiles);
    hipLaunchKernelGGL(k_bn, dim3((N*64+255)/256), dim3(256), 0, stream,
                       zb, colsums, gam + (size_t)l*HID, bet + (size_t)l*HID,
                       h, (unsigned*)xb, N*64, 1.0f/(float)N);
  }
}